// Round 3
// baseline (194.139 us; speedup 1.0000x reference)
//
#include <hip/hip_runtime.h>

// B=32, S=127, new_seq=128, D=768, H=12, HD=64
#define NB 32
#define NS 128
#define SD 127
#define ND 768
#define NH 12
#define HD 64

__device__ inline float wredSum(float v){
  #pragma unroll
  for (int off=32; off>0; off>>=1) v += __shfl_xor(v, off);
  return v;
}
__device__ inline float wredMax(float v){
  #pragma unroll
  for (int off=32; off>0; off>>=1) v = fmaxf(v, __shfl_xor(v, off));
  return v;
}

// One block per (b,h). Everything for this (b,h) lives in LDS; no workspace,
// no inter-kernel dependencies. uk (Wk folded with wk_a) is recomputed per
// block: 49k MAC + 192 KB L2 reads -- cheaper than a separate kernel launch.
__global__ __launch_bounds__(512)
void mega(const float* __restrict__ desc, const float* __restrict__ nv,
          const float* __restrict__ Wk, const float* __restrict__ bk,
          const float* __restrict__ Wv, const float* __restrict__ bv,
          const float* __restrict__ Wa, float* __restrict__ out){
  int bh = blockIdx.x, b = bh/NH, h = bh%NH;
  int t = threadIdx.x, wave = t>>6, lane = t&63;
  __shared__ float uk[ND];          // folded K row for head h
  __shared__ float lkr[NS];         // lk[b,h,j]
  __shared__ float eh[NS], ehm[NS]; // ei[b,h,s], ei[b,h%6,s]
  __shared__ float w0[NS], w1[NS];  // softmax weights: row 0, rows >=1
  __shared__ float m0[ND], m1[ND];  // attn-weighted nv rows
  __shared__ float c0[HD], c1[HD];  // ctx vectors
  __shared__ float bkd;             // bk_h . wk_a

  // ---- phase 0: fold uk[c] = sum_d Wk[h*64+d, c] * wk_a[d] ----
  {
    const float* wkrow = Wk + (size_t)(h*HD)*ND;
    float a0=0.f, a1=0.f;
    #pragma unroll 8
    for (int d=0; d<64; ++d){
      float wa = Wa[64+d];                      // uniform -> scalar load
      a0 += wkrow[(size_t)d*ND + t] * wa;
      if (t < 256) a1 += wkrow[(size_t)d*ND + t + 512] * wa;
    }
    uk[t] = a0;
    if (t < 256) uk[t+512] = a1;
    if (wave == 0){
      float v = bk[h*64+lane]*Wa[64+lane];
      v = wredSum(v);
      if (lane==0) bkd = v;
    }
  }
  __syncthreads();

  // ---- phase 1: lk row (128 wave-dots of 768) + ei slices ----
  float wea = Wa[128+lane];
  {
    const float* nvb = nv + (size_t)(b*NS)*ND;
    for (int jj=0; jj<16; ++jj){
      int j = wave*16 + jj;
      const float* row = nvb + (size_t)j*ND;
      float acc = 0.f;
      #pragma unroll
      for (int k=0; k<12; ++k) acc += row[lane+64*k]*uk[lane+64*k];
      acc = wredSum(acc);
      if (lane==0) lkr[j] = acc + bkd;
    }
    int hm = h % 6;
    for (int tau = wave; tau < 2*SD; tau += 8){
      int isB = (tau >= SD);
      int s   = isB ? tau - SD : tau;
      int col = isB ? hm : h;
      float v = desc[(size_t)(b*SD+s)*ND + col*64 + lane] * wea;
      v = wredSum(v);
      if (lane==0){ if (isB) ehm[s] = v; else eh[s] = v; }
    }
  }
  __syncthreads();

  // ---- phase 2: the two softmaxes (col 0 masked) ----
  if (wave < 2){
    float x0, x1;
    if (wave == 0){                       // row i=0: + ei[b, h%6, j-1]
      x0 = (lane>=1) ? lkr[lane] + ehm[lane-1] : -3.0e38f;
      x1 = lkr[lane+64] + ehm[lane+63];
    } else {                              // rows i>=1: + (h>=6 ? ei[b,h,j-1] : 0)
      float g = (h>=6) ? 1.f : 0.f;
      x0 = (lane>=1) ? lkr[lane] + g*eh[lane-1] : -3.0e38f;
      x1 = lkr[lane+64] + g*eh[lane+63];
    }
    float mm = wredMax(fmaxf(x0,x1));
    float e0 = (lane>=1) ? expf(x0-mm) : 0.f;   // lane0 -> exactly 0 (masked)
    float e1 = expf(x1-mm);
    float s  = wredSum(e0+e1);
    float inv = 1.f/s;
    float* wd = wave ? w1 : w0;
    wd[lane]    = e0*inv;
    wd[lane+64] = e1*inv;
  }
  __syncthreads();

  // ---- phase 3: m[c] = sum_j w[j] * nv[b,j,c] ----
  {
    const float* nvb = nv + (size_t)(b*NS)*ND;
    float a00=0.f, a01=0.f, a10=0.f, a11=0.f;
    for (int j=1; j<NS; ++j){
      float wj0 = w0[j], wj1 = w1[j];     // LDS broadcast
      float x0 = nvb[(size_t)j*ND + t];
      a00 += wj0*x0; a10 += wj1*x0;
      if (t < 256){
        float x1 = nvb[(size_t)j*ND + t + 512];
        a01 += wj0*x1; a11 += wj1*x1;
      }
    }
    m0[t] = a00; m1[t] = a10;
    if (t < 256){ m0[t+512] = a01; m1[t+512] = a11; }
  }
  __syncthreads();

  // ---- phase 4: ctx[d] = m . Wv[h*64+d,:] + bv ----
  {
    #pragma unroll
    for (int dd=0; dd<8; ++dd){
      int d = wave*8 + dd;
      const float* wvr = Wv + (size_t)(h*HD+d)*ND;
      float p0=0.f, p1=0.f;
      #pragma unroll
      for (int k=0; k<12; ++k){
        float wv = wvr[lane+64*k];
        p0 += wv*m0[lane+64*k];
        p1 += wv*m1[lane+64*k];
      }
      p0 = wredSum(p0); p1 = wredSum(p1);
      if (lane==0){
        float bb = bv[h*HD+d];
        c0[d] = p0+bb; c1[d] = p1+bb;
      }
    }
  }
  __syncthreads();

  // ---- phase 5: write attn block + basis slice ----
  {
    float4* ao = (float4*)(out + (size_t)NB*NS*ND + (size_t)bh*NS*NS);
    for (int idx=t; idx<NS*32; idx+=512){
      int i = idx>>5, q = idx&31;
      const float* src = (i==0) ? w0 : w1;
      float4 v = { src[q*4], src[q*4+1], src[q*4+2], src[q*4+3] };
      ao[idx] = v;
    }
    float* bo = out + (size_t)b*NS*ND + h*HD;
    for (int idx=t; idx<NS*16; idx+=512){
      int i = idx>>4, q = idx&15;
      const float* src = (i==0) ? c0 : c1;
      float4 v = { src[q*4], src[q*4+1], src[q*4+2], src[q*4+3] };
      *(float4*)(bo + (size_t)i*ND + q*4) = v;
    }
  }
}

extern "C" void kernel_launch(void* const* d_in, const int* in_sizes, int n_in,
                              void* d_out, int out_size, void* d_ws, size_t ws_size,
                              hipStream_t stream) {
  const float* desc = (const float*)d_in[0];
  const float* nv   = (const float*)d_in[1];
  // d_in[2]=Wq, d_in[3]=bq: unused (softmax shift-invariance)
  const float* Wk   = (const float*)d_in[4];
  const float* bk   = (const float*)d_in[5];
  const float* Wv   = (const float*)d_in[6];
  const float* bv   = (const float*)d_in[7];
  const float* Wa   = (const float*)d_in[8];
  // d_in[9]=ba: unused (constant shift)
  float* out = (float*)d_out;

  mega<<<NB*NH, 512, 0, stream>>>(desc, nv, Wk, bk, Wv, bv, Wa, out);
}

// Round 4
// 154.869 us; speedup vs baseline: 1.2536x; 1.2536x over previous
//
#include <hip/hip_runtime.h>

// B=32, S=127, new_seq=128, D=768, H=12, HD=64
#define NB 32
#define NS 128
#define SD 127
#define ND 768
#define NH 12
#define HD 64

__device__ inline float wredSum(float v){
  #pragma unroll
  for (int off=32; off>0; off>>=1) v += __shfl_xor(v, off);
  return v;
}
__device__ inline float wredMax(float v){
  #pragma unroll
  for (int off=32; off>0; off>>=1) v = fmaxf(v, __shfl_xor(v, off));
  return v;
}

// K0: uk[h][c] = sum_d Wk[h*64+d, c] * wk_a[d]; bkdot[h] = bk_h . wk_a
__global__ void fold_k(const float* __restrict__ Wk, const float* __restrict__ bk,
                       const float* __restrict__ Wa, float* __restrict__ uk,
                       float* __restrict__ bkdot){
  int t = blockIdx.x*256 + threadIdx.x;       // 0..9215
  int h = t / ND, c = t % ND;
  const float* wka = Wa + 64;
  float acc = 0.f;
  #pragma unroll 8
  for (int d=0; d<64; ++d) acc += Wk[(size_t)(h*HD+d)*ND + c] * wka[d];
  uk[h*ND + c] = acc;
  if (blockIdx.x==0 && threadIdx.x < NH){
    int hh = threadIdx.x; float a = 0.f;
    for (int d=0; d<64; ++d) a += bk[hh*HD+d]*wka[d];
    bkdot[hh] = a;
  }
}

// K1: blocks [0,4096) lk rows; [4096,8160) ei rows; [8160,8208) ctx := bias
__global__ __launch_bounds__(256)
void lk_ei_init(const float* __restrict__ nv, const float* __restrict__ desc,
                const float* __restrict__ uk, const float* __restrict__ bkdot,
                const float* __restrict__ Wa, const float* __restrict__ bv,
                float* __restrict__ lk, float* __restrict__ ei,
                float* __restrict__ ctx){
  __shared__ float sh[ND];
  int blk = blockIdx.x;
  int wave = threadIdx.x >> 6, lane = threadIdx.x & 63;
  if (blk < NB*NS){
    int b = blk >> 7, j = blk & 127;
    const float* row = nv + (size_t)blk * ND;
    for (int c = threadIdx.x; c < ND; c += 256) sh[c] = row[c];
    __syncthreads();
    #pragma unroll
    for (int hh=0; hh<3; ++hh){
      int h = wave*3 + hh;
      float acc = 0.f;
      #pragma unroll
      for (int k=0; k<12; ++k) acc += sh[lane+64*k]*uk[h*ND + lane+64*k];
      acc = wredSum(acc);
      if (lane==0) lk[(b*NH + h)*NS + j] = acc + bkdot[h];
    }
  } else if (blk < NB*NS + NB*SD){
    int bs = blk - NB*NS;                 // 0..4063
    int b = bs / SD, s = bs % SD;
    float wea = Wa[128 + lane];
    const float* row = desc + (size_t)bs * ND;
    #pragma unroll
    for (int hh=0; hh<3; ++hh){
      int h = wave + hh*4;
      float v = row[h*HD + lane] * wea;
      v = wredSum(v);
      if (lane==0) ei[(b*NH + h)*NS + s] = v;
    }
  } else {
    // init ctx[b][r][d] = bv[h*64+d], r = 2h+which; 12288 float4s
    int idx = (blk - (NB*NS + NB*SD))*256 + threadIdx.x;
    int dq = idx & 15;
    int r  = (idx >> 4) % 24;
    int h  = r >> 1;
    const float* bb = bv + h*HD + dq*4;
    float4 v = { bb[0], bb[1], bb[2], bb[3] };
    ((float4*)ctx)[idx] = v;
  }
}

// K2: block = (b,h,cc). Softmax (redundant x3, cheap) -> m chunk -> partial
// V-projection -> atomicAdd into ctx. cc==0 also saves w for K3.
__global__ __launch_bounds__(256)
void wm_proj(const float* __restrict__ nv, const float* __restrict__ lk,
             const float* __restrict__ ei, const float* __restrict__ Wv,
             float* __restrict__ w, float* __restrict__ ctx){
  int blk = blockIdx.x;               // b*36 + h*3 + cc
  int cc = blk % 3, bh = blk / 3;
  int b = bh / NH, h = bh % NH;
  __shared__ float w0[NS], w1[NS], m0[256], m1[256];
  int t = threadIdx.x, wave = t >> 6, lane = t & 63;

  if (wave < 2){
    const float* lkrow = lk + bh*NS;
    const float* eirow = ei + (b*NH + (wave==0 ? (h%6) : h))*NS;
    float g = (wave==0) ? 1.f : (h>=6 ? 1.f : 0.f);
    float x0 = (lane>=1) ? lkrow[lane] + g*eirow[lane-1] : -3.0e38f;
    float x1 = lkrow[lane+64] + g*eirow[lane+63];
    float mm = wredMax(fmaxf(x0,x1));
    float e0 = (lane>=1) ? expf(x0-mm) : 0.f;   // col 0 masked -> exactly 0
    float e1 = expf(x1-mm);
    float s  = wredSum(e0+e1);
    float inv = 1.f/s;
    float* wd = wave ? w1 : w0;
    wd[lane]    = e0*inv;
    wd[lane+64] = e1*inv;
  }
  __syncthreads();
  if (cc == 0 && t < NS){
    w[(bh*2 + 0)*NS + t] = w0[t];
    w[(bh*2 + 1)*NS + t] = w1[t];
  }

  // m chunk: c = cc*256 + t
  const float* nvp = nv + (size_t)(b*NS)*ND + cc*256 + t;
  float a0 = 0.f, a1 = 0.f;
  #pragma unroll 4
  for (int j=1; j<NS; ++j){
    float x = nvp[(size_t)j*ND];
    a0 += w0[j]*x;
    a1 += w1[j]*x;
  }
  m0[t] = a0; m1[t] = a1;
  __syncthreads();

  // partial projection over this c chunk; wave -> d range
  const float* wvbase = Wv + (size_t)(h*HD)*ND + cc*256;
  #pragma unroll 4
  for (int dd=0; dd<16; ++dd){
    int d = wave*16 + dd;
    const float* wvr = wvbase + (size_t)d*ND;
    float p0 = 0.f, p1 = 0.f;
    #pragma unroll
    for (int k=0; k<4; ++k){
      float wv = wvr[lane + 64*k];
      p0 += wv*m0[lane + 64*k];
      p1 += wv*m1[lane + 64*k];
    }
    p0 = wredSum(p0); p1 = wredSum(p1);
    if (lane==0){
      atomicAdd(&ctx[((size_t)b*24 + h*2    )*HD + d], p0);
      atomicAdd(&ctx[((size_t)b*24 + h*2 + 1)*HD + d], p1);
    }
  }
}

// K3: one float4 per thread: [0,786432) basis, [786432, 2359296) attn
__global__ __launch_bounds__(256)
void write_kernel(const float* __restrict__ ctx, const float* __restrict__ w,
                  float* __restrict__ out){
  int idx = blockIdx.x*256 + threadIdx.x;
  const float4* c4 = (const float4*)ctx;
  const float4* w4 = (const float4*)w;
  float4* o4 = (float4*)out;
  if (idx < 786432){
    int dq = idx & 15;
    int h  = (idx >> 4) % NH;
    int i  = (idx / 192) & 127;
    int b  = idx / 24576;
    o4[idx] = c4[((b*NH + h)*2 + (i != 0))*16 + dq];
  } else {
    int q  = idx - 786432;
    int j4 = q & 31;
    int i  = (q >> 5) & 127;
    int bh = q >> 12;
    o4[idx] = w4[(bh*2 + (i != 0))*32 + j4];
  }
}

extern "C" void kernel_launch(void* const* d_in, const int* in_sizes, int n_in,
                              void* d_out, int out_size, void* d_ws, size_t ws_size,
                              hipStream_t stream) {
  const float* desc = (const float*)d_in[0];
  const float* nv   = (const float*)d_in[1];
  // d_in[2]=Wq, d_in[3]=bq: unused (softmax shift-invariance)
  const float* Wk   = (const float*)d_in[4];
  const float* bk   = (const float*)d_in[5];
  const float* Wv   = (const float*)d_in[6];
  const float* bv   = (const float*)d_in[7];
  const float* Wa   = (const float*)d_in[8];
  // d_in[9]=ba: unused (constant shift)
  float* out = (float*)d_out;
  float* ws  = (float*)d_ws;

  float* uk    = ws;              // 9216
  float* bkdot = ws + 9216;       // 16
  float* ei    = ws + 9232;       // 49152
  float* lkbuf = ws + 58384;      // 49152
  float* wbuf  = ws + 107536;     // 98304   [bh][which][j]
  float* ctx   = ws + 205840;     // 49152   [b][2h+which][d]

  fold_k      <<<36,   256, 0, stream>>>(Wk, bk, Wa, uk, bkdot);
  lk_ei_init  <<<8208, 256, 0, stream>>>(nv, desc, uk, bkdot, Wa, bv, lkbuf, ei, ctx);
  wm_proj     <<<1152, 256, 0, stream>>>(nv, lkbuf, ei, Wv, wbuf, ctx);
  write_kernel<<<9216, 256, 0, stream>>>(ctx, wbuf, out);
}

// Round 5
// 150.819 us; speedup vs baseline: 1.2872x; 1.0269x over previous
//
#include <hip/hip_runtime.h>

// B=32, S=127, new_seq=128, D=768, H=12, HD=64
#define NB 32
#define NS 128
#define SD 127
#define ND 768
#define NH 12
#define HD 64

__device__ inline float wredSum(float v){
  #pragma unroll
  for (int off=32; off>0; off>>=1) v += __shfl_xor(v, off);
  return v;
}
__device__ inline float wredMax(float v){
  #pragma unroll
  for (int off=32; off>0; off>>=1) v = fmaxf(v, __shfl_xor(v, off));
  return v;
}

// K0: uk[h][c] = sum_d Wk[h*64+d, c] * wk_a[d].  Grid 144 = (h, c-chunk of 64);
// d split across 4 wave-groups + LDS reduce -> 16 independent loads/thread.
__global__ __launch_bounds__(256)
void fold_k(const float* __restrict__ Wk, const float* __restrict__ bk,
            const float* __restrict__ Wa, float* __restrict__ uk,
            float* __restrict__ bkdot){
  int blk = blockIdx.x;             // h*12 + cb
  int h = blk/12, cb = blk%12;
  int t = threadIdx.x;
  int c0 = t & 63, dg = t >> 6;
  const float* base = Wk + (size_t)(h*HD + dg*16)*ND + cb*64 + c0;
  float acc = 0.f;
  #pragma unroll
  for (int i=0;i<16;++i) acc += base[(size_t)i*ND] * Wa[64 + dg*16 + i];
  __shared__ float red[4][64];
  red[dg][c0] = acc;
  __syncthreads();
  if (dg==0) uk[h*ND + cb*64 + c0] = red[0][c0]+red[1][c0]+red[2][c0]+red[3][c0];
  if (blk==0 && t < NH){
    float a = 0.f;
    for (int d=0; d<64; ++d) a += bk[t*HD+d]*Wa[64+d];
    bkdot[t] = a;
  }
}

// K1: blocks [0,4096) lk rows; [4096,8160) ei rows; [8160,8208) ctx := bias
__global__ __launch_bounds__(256)
void lk_ei_init(const float* __restrict__ nv, const float* __restrict__ desc,
                const float* __restrict__ uk, const float* __restrict__ bkdot,
                const float* __restrict__ Wa, const float* __restrict__ bv,
                float* __restrict__ lk, float* __restrict__ ei,
                float* __restrict__ ctx){
  __shared__ float sh[ND];
  int blk = blockIdx.x;
  int wave = threadIdx.x >> 6, lane = threadIdx.x & 63;
  if (blk < NB*NS){
    int b = blk >> 7, j = blk & 127;
    const float* row = nv + (size_t)blk * ND;
    for (int c = threadIdx.x; c < ND; c += 256) sh[c] = row[c];
    __syncthreads();
    #pragma unroll
    for (int hh=0; hh<3; ++hh){
      int h = wave*3 + hh;
      float acc = 0.f;
      #pragma unroll
      for (int k=0; k<12; ++k) acc += sh[lane+64*k]*uk[h*ND + lane+64*k];
      acc = wredSum(acc);
      if (lane==0) lk[(b*NH + h)*NS + j] = acc + bkdot[h];
    }
  } else if (blk < NB*NS + NB*SD){
    int bs = blk - NB*NS;                 // 0..4063
    int b = bs / SD, s = bs % SD;
    float wea = Wa[128 + lane];
    const float* row = desc + (size_t)bs * ND;
    #pragma unroll
    for (int hh=0; hh<3; ++hh){
      int h = wave + hh*4;
      float v = row[h*HD + lane] * wea;
      v = wredSum(v);
      if (lane==0) ei[(b*NH + h)*NS + s] = v;
    }
  } else {
    // ctx[b][r][d] = bv[h*64+d], r = 2h+which; 12288 float4s
    int idx = (blk - (NB*NS + NB*SD))*256 + threadIdx.x;
    int dq = idx & 15;
    int r  = (idx >> 4) % 24;
    int h  = r >> 1;
    const float* bb = bv + h*HD + dq*4;
    float4 v = { bb[0], bb[1], bb[2], bb[3] };
    ((float4*)ctx)[idx] = v;
  }
}

// K2: block = (b,h,cc).  Softmax (redundant x3) -> attn rows r%3==cc written
// straight from LDS (overlaps the m-loop's loads) -> m chunk -> partial
// V-projection -> atomicAdd into ctx.
__global__ __launch_bounds__(256)
void wm_proj(const float* __restrict__ nv, const float* __restrict__ lk,
             const float* __restrict__ ei, const float* __restrict__ Wv,
             float* __restrict__ ctx, float* __restrict__ out){
  int blk = blockIdx.x;               // b*36 + h*3 + cc
  int cc = blk % 3, bh = blk / 3;
  int b = bh / NH, h = bh % NH;
  __shared__ float w0[NS], w1[NS], m0[256], m1[256];
  int t = threadIdx.x, wave = t >> 6, lane = t & 63;

  if (wave < 2){
    const float* lkrow = lk + bh*NS;
    const float* eirow = ei + (b*NH + (wave==0 ? (h%6) : h))*NS;
    float g = (wave==0) ? 1.f : (h>=6 ? 1.f : 0.f);
    float x0 = (lane>=1) ? lkrow[lane] + g*eirow[lane-1] : -3.0e38f;
    float x1 = lkrow[lane+64] + g*eirow[lane+63];
    float mm = wredMax(fmaxf(x0,x1));
    float e0 = (lane>=1) ? __expf(x0-mm) : 0.f;   // col 0 masked -> exactly 0
    float e1 = __expf(x1-mm);
    float s  = wredSum(e0+e1);
    float inv = 1.f/s;
    float* wd = wave ? w1 : w0;
    wd[lane]    = e0*inv;
    wd[lane+64] = e1*inv;
  }
  __syncthreads();

  // attn rows r = cc, cc+3, ... (row 0 = w0, others = w1); fire-and-forget
  {
    float4* ao = (float4*)(out + (size_t)NB*NS*ND + (size_t)bh*NS*NS);
    int nrows = (NS - cc + 2)/3;
    for (int idx=t; idx<nrows*32; idx+=256){
      int rr = idx>>5, q = idx&31;
      int r = cc + 3*rr;
      const float* src = (r==0) ? w0 : w1;
      float4 v = { src[q*4], src[q*4+1], src[q*4+2], src[q*4+3] };
      ao[r*32+q] = v;
    }
  }

  // m chunk: c = cc*256 + t
  const float* nvp = nv + (size_t)(b*NS)*ND + cc*256 + t;
  float a0 = 0.f, a1 = 0.f;
  #pragma unroll 4
  for (int j=1; j<NS; ++j){
    float x = nvp[(size_t)j*ND];
    a0 += w0[j]*x;
    a1 += w1[j]*x;
  }
  m0[t] = a0; m1[t] = a1;
  __syncthreads();

  // partial projection over this c chunk; wave -> d range
  const float* wvbase = Wv + (size_t)(h*HD)*ND + cc*256;
  #pragma unroll 4
  for (int dd=0; dd<16; ++dd){
    int d = wave*16 + dd;
    const float* wvr = wvbase + (size_t)d*ND;
    float p0 = 0.f, p1 = 0.f;
    #pragma unroll
    for (int k=0; k<4; ++k){
      float wv = wvr[lane + 64*k];
      p0 += wv*m0[lane + 64*k];
      p1 += wv*m1[lane + 64*k];
    }
    p0 = wredSum(p0); p1 = wredSum(p1);
    if (lane==0){
      atomicAdd(&ctx[((size_t)b*24 + h*2    )*HD + d], p0);
      atomicAdd(&ctx[((size_t)b*24 + h*2 + 1)*HD + d], p1);
    }
  }
}

// K3: basis only. One float4 per thread, 786432 total.
__global__ __launch_bounds__(256)
void basis_kernel(const float* __restrict__ ctx, float* __restrict__ out){
  int idx = blockIdx.x*256 + threadIdx.x;
  int dq = idx & 15;
  int h  = (idx >> 4) % NH;
  int i  = (idx / 192) & 127;
  int b  = idx / 24576;
  ((float4*)out)[idx] = ((const float4*)ctx)[((b*NH + h)*2 + (i != 0))*16 + dq];
}

extern "C" void kernel_launch(void* const* d_in, const int* in_sizes, int n_in,
                              void* d_out, int out_size, void* d_ws, size_t ws_size,
                              hipStream_t stream) {
  const float* desc = (const float*)d_in[0];
  const float* nv   = (const float*)d_in[1];
  // d_in[2]=Wq, d_in[3]=bq: unused (softmax shift-invariance)
  const float* Wk   = (const float*)d_in[4];
  const float* bk   = (const float*)d_in[5];
  const float* Wv   = (const float*)d_in[6];
  const float* bv   = (const float*)d_in[7];
  const float* Wa   = (const float*)d_in[8];
  // d_in[9]=ba: unused (constant shift)
  float* out = (float*)d_out;
  float* ws  = (float*)d_ws;

  float* uk    = ws;              // 9216
  float* bkdot = ws + 9216;       // 16
  float* ei    = ws + 9232;       // 49152
  float* lkbuf = ws + 58384;      // 49152
  float* ctx   = ws + 107536;     // 49152   [b][2h+which][d]

  fold_k      <<<144,  256, 0, stream>>>(Wk, bk, Wa, uk, bkdot);
  lk_ei_init  <<<8208, 256, 0, stream>>>(nv, desc, uk, bkdot, Wa, bv, lkbuf, ei, ctx);
  wm_proj     <<<1152, 256, 0, stream>>>(nv, lkbuf, ei, Wv, ctx, out);
  basis_kernel<<<3072, 256, 0, stream>>>(ctx, out);
}

// Round 6
// 143.036 us; speedup vs baseline: 1.3573x; 1.0544x over previous
//
#include <hip/hip_runtime.h>

// B=32, S=127, new_seq=128, D=768, H=12, HD=64
#define NB 32
#define NS 128
#define SD 127
#define ND 768
#define NH 12
#define HD 64

__device__ inline float wredSum(float v){
  #pragma unroll
  for (int off=32; off>0; off>>=1) v += __shfl_xor(v, off);
  return v;
}
__device__ inline float wredMax(float v){
  #pragma unroll
  for (int off=32; off>0; off>>=1) v = fmaxf(v, __shfl_xor(v, off));
  return v;
}

// K0: uk[h][c] = sum_d Wk[h*64+d, c] * wk_a[d].  144 blocks = (h, c-chunk of 64).
__global__ __launch_bounds__(256)
void fold_k(const float* __restrict__ Wk, const float* __restrict__ bk,
            const float* __restrict__ Wa, float* __restrict__ uk,
            float* __restrict__ bkdot){
  int blk = blockIdx.x;             // h*12 + cb
  int h = blk/12, cb = blk%12;
  int t = threadIdx.x;
  int c0 = t & 63, dg = t >> 6;
  const float* base = Wk + (size_t)(h*HD + dg*16)*ND + cb*64 + c0;
  float acc = 0.f;
  #pragma unroll
  for (int i=0;i<16;++i) acc += base[(size_t)i*ND] * Wa[64 + dg*16 + i];
  __shared__ float red[4][64];
  red[dg][c0] = acc;
  __syncthreads();
  if (dg==0) uk[h*ND + cb*64 + c0] = red[0][c0]+red[1][c0]+red[2][c0]+red[3][c0];
  if (blk==0 && t < NH){
    float a = 0.f;
    for (int d=0; d<64; ++d) a += bk[t*HD+d]*Wa[64+d];
    bkdot[t] = a;
  }
}

// K1: blocks [0,4096) lk rows; [4096,8160) ei rows
__global__ __launch_bounds__(256)
void lk_ei(const float* __restrict__ nv, const float* __restrict__ desc,
           const float* __restrict__ uk, const float* __restrict__ bkdot,
           const float* __restrict__ Wa,
           float* __restrict__ lk, float* __restrict__ ei){
  __shared__ float sh[ND];
  int blk = blockIdx.x;
  int wave = threadIdx.x >> 6, lane = threadIdx.x & 63;
  if (blk < NB*NS){
    int b = blk >> 7, j = blk & 127;
    const float* row = nv + (size_t)blk * ND;
    for (int c = threadIdx.x; c < ND; c += 256) sh[c] = row[c];
    __syncthreads();
    #pragma unroll
    for (int hh=0; hh<3; ++hh){
      int h = wave*3 + hh;
      float acc = 0.f;
      #pragma unroll
      for (int k=0; k<12; ++k) acc += sh[lane+64*k]*uk[h*ND + lane+64*k];
      acc = wredSum(acc);
      if (lane==0) lk[(b*NH + h)*NS + j] = acc + bkdot[h];
    }
  } else {
    int bs = blk - NB*NS;                 // 0..4063
    int b = bs / SD, s = bs % SD;
    float wea = Wa[128 + lane];
    const float* row = desc + (size_t)bs * ND;
    #pragma unroll
    for (int hh=0; hh<3; ++hh){
      int h = wave + hh*4;
      float v = row[h*HD + lane] * wea;
      v = wredSum(v);
      if (lane==0) ei[(b*NH + h)*NS + s] = v;
    }
  }
}

// K2: per (b,h) the two softmaxes. wave0 -> row-0 dist (w index 0),
// wave1 -> rows>=1 dist (w index 1).  Writes w and transposed wT[b][j][r].
__global__ __launch_bounds__(128)
void softmax_k(const float* __restrict__ lk, const float* __restrict__ ei,
               float* __restrict__ w, float* __restrict__ wT){
  int bh = blockIdx.x;                // 0..383
  int b = bh / NH, h = bh % NH;
  int t = threadIdx.x, wave = t >> 6, lane = t & 63;
  const float* lkrow = lk + bh*NS;
  const float* eirow = ei + (b*NH + (wave==0 ? (h%6) : h))*NS;
  float g = (wave==0) ? 1.f : (h>=6 ? 1.f : 0.f);
  float x0 = (lane>=1) ? lkrow[lane] + g*eirow[lane-1] : -3.0e38f;
  float x1 = lkrow[lane+64] + g*eirow[lane+63];
  float mm = wredMax(fmaxf(x0,x1));
  float e0 = (lane>=1) ? __expf(x0-mm) : 0.f;   // col 0 masked -> exactly 0
  float e1 = __expf(x1-mm);
  float s  = wredSum(e0+e1);
  float inv = 1.f/s;
  float v0 = e0*inv, v1 = e1*inv;
  w[(bh*2+wave)*NS + lane]      = v0;
  w[(bh*2+wave)*NS + lane+64]   = v1;
  int r = h*2 + wave;
  wT[(b*NS + lane)*24 + r]      = v0;
  wT[(b*NS + lane+64)*24 + r]   = v1;
}

// K3: m partials.  Block = (b, jg of 32 j's); 192 threads each own 4 c's.
// One float4 nv load feeds 96 FMAs -> latency amortized; nv read exactly once.
// j=0 is included but wT[b][0][*] == 0 exactly, so it contributes nothing.
__global__ __launch_bounds__(192)
void m_kernel(const float* __restrict__ nv, const float* __restrict__ wT,
              float* __restrict__ m_part){
  int blk = blockIdx.x;               // b*4 + jg
  int b = blk >> 2, jg = blk & 3;
  int t = threadIdx.x;                // 0..191
  __shared__ float wld[32][24];
  for (int i=t; i<32*24; i+=192) ((float*)wld)[i] = wT[(size_t)(b*NS + jg*32)*24 + i];
  __syncthreads();
  const float4* nvb = (const float4*)(nv + ((size_t)b*NS + jg*32)*ND);
  float4 acc[24];
  #pragma unroll
  for (int r=0; r<24; ++r) acc[r] = make_float4(0.f,0.f,0.f,0.f);
  #pragma unroll 2
  for (int jj=0; jj<32; ++jj){
    float4 x = nvb[jj*192 + t];
    #pragma unroll
    for (int r=0; r<24; ++r){
      float wr = wld[jj][r];
      acc[r].x += wr*x.x; acc[r].y += wr*x.y;
      acc[r].z += wr*x.z; acc[r].w += wr*x.w;
    }
  }
  #pragma unroll
  for (int r=0; r<24; ++r){
    ((float4*)(m_part + ((size_t)(b*24 + r)*4 + jg)*ND))[t] = acc[r];
  }
}

// K4: per (b,h): sum 4 m-partials -> V-projection -> write attn tile + basis slice.
__global__ __launch_bounds__(256)
void proj_write(const float* __restrict__ m_part, const float* __restrict__ Wv,
                const float* __restrict__ bv, const float* __restrict__ w,
                float* __restrict__ out){
  int bh = blockIdx.x;                // 0..383
  int b = bh / NH, h = bh % NH;
  int t = threadIdx.x, wave = t >> 6, lane = t & 63;
  __shared__ float msum[2][ND];
  __shared__ float wrow[2][NS];
  __shared__ float cvec[2][HD];
  wrow[t>>7][t&127] = w[(size_t)bh*2*NS + t];
  for (int i=t; i<2*ND; i+=256){
    int rl = (i >= ND);
    int c  = i - rl*ND;
    const float* mp = m_part + ((size_t)(b*24 + h*2 + rl)*4)*ND + c;
    msum[rl][c] = mp[0] + mp[ND] + mp[2*ND] + mp[3*ND];
  }
  __syncthreads();
  #pragma unroll 4
  for (int dd=0; dd<16; ++dd){
    int d = wave*16 + dd;
    const float* wvr = Wv + (size_t)(h*HD + d)*ND;
    float p0=0.f, p1=0.f;
    #pragma unroll
    for (int k=0; k<12; ++k){
      float wv = wvr[lane + 64*k];
      p0 += wv*msum[0][lane + 64*k];
      p1 += wv*msum[1][lane + 64*k];
    }
    p0 = wredSum(p0); p1 = wredSum(p1);
    if (lane==0){
      float bb = bv[h*HD + d];
      cvec[0][d] = p0 + bb;
      cvec[1][d] = p1 + bb;
    }
  }
  __syncthreads();
  // attn tile: 128x128 floats = 4096 float4
  float4* ao = (float4*)(out + (size_t)NB*NS*ND + (size_t)bh*NS*NS);
  for (int idx=t; idx<4096; idx+=256){
    int i = idx>>5, q = idx&31;
    const float* src = (i==0) ? wrow[0] : wrow[1];
    float4 v = { src[q*4], src[q*4+1], src[q*4+2], src[q*4+3] };
    ao[idx] = v;
  }
  // basis slice: out[b][i][h*64 + q*4], 128 x 16 float4
  float* bo = out + (size_t)b*NS*ND + h*HD;
  for (int idx=t; idx<2048; idx+=256){
    int i = idx>>4, q = idx&15;
    const float* src = (i==0) ? cvec[0] : cvec[1];
    float4 v = { src[q*4], src[q*4+1], src[q*4+2], src[q*4+3] };
    *(float4*)(bo + (size_t)i*ND + q*4) = v;
  }
}

extern "C" void kernel_launch(void* const* d_in, const int* in_sizes, int n_in,
                              void* d_out, int out_size, void* d_ws, size_t ws_size,
                              hipStream_t stream) {
  const float* desc = (const float*)d_in[0];
  const float* nv   = (const float*)d_in[1];
  // d_in[2]=Wq, d_in[3]=bq: unused (softmax shift-invariance)
  const float* Wk   = (const float*)d_in[4];
  const float* bk   = (const float*)d_in[5];
  const float* Wv   = (const float*)d_in[6];
  const float* bv   = (const float*)d_in[7];
  const float* Wa   = (const float*)d_in[8];
  // d_in[9]=ba: unused (constant shift)
  float* out = (float*)d_out;
  float* ws  = (float*)d_ws;

  float* uk     = ws;               // 9216
  float* bkdot  = ws + 9216;        // 16
  float* ei     = ws + 9232;        // 49152
  float* lkbuf  = ws + 58384;       // 49152
  float* wbuf   = ws + 107536;      // 98304   [bh][which][j]
  float* wT     = ws + 205840;      // 98304   [b][j][r=2h+which]
  float* m_part = ws + 304144;      // 2359296 [b][r][jg][c]

  fold_k    <<<144,  256, 0, stream>>>(Wk, bk, Wa, uk, bkdot);
  lk_ei     <<<8160, 256, 0, stream>>>(nv, desc, uk, bkdot, Wa, lkbuf, ei);
  softmax_k <<<384,  128, 0, stream>>>(lkbuf, ei, wbuf, wT);
  m_kernel  <<<128,  192, 0, stream>>>(nv, wT, m_part);
  proj_write<<<384,  256, 0, stream>>>(m_part, Wv, bv, wbuf, out);
}

// Round 7
// 139.821 us; speedup vs baseline: 1.3885x; 1.0230x over previous
//
#include <hip/hip_runtime.h>

// B=32, S=127, new_seq=128, D=768, H=12, HD=64
#define NB 32
#define NS 128
#define SD 127
#define ND 768
#define NH 12
#define HD 64

__device__ inline float wredSum(float v){
  #pragma unroll
  for (int off=32; off>0; off>>=1) v += __shfl_xor(v, off);
  return v;
}
__device__ inline float wredMax(float v){
  #pragma unroll
  for (int off=32; off>0; off>>=1) v = fmaxf(v, __shfl_xor(v, off));
  return v;
}

// K0: uk[h][c] = sum_d Wk[h*64+d, c] * wk_a[d].  144 blocks = (h, c-chunk of 64).
__global__ __launch_bounds__(256)
void fold_k(const float* __restrict__ Wk, const float* __restrict__ bk,
            const float* __restrict__ Wa, float* __restrict__ uk,
            float* __restrict__ bkdot){
  int blk = blockIdx.x;             // h*12 + cb
  int h = blk/12, cb = blk%12;
  int t = threadIdx.x;
  int c0 = t & 63, dg = t >> 6;
  const float* base = Wk + (size_t)(h*HD + dg*16)*ND + cb*64 + c0;
  float acc = 0.f;
  #pragma unroll
  for (int i=0;i<16;++i) acc += base[(size_t)i*ND] * Wa[64 + dg*16 + i];
  __shared__ float red[4][64];
  red[dg][c0] = acc;
  __syncthreads();
  if (dg==0) uk[h*ND + cb*64 + c0] = red[0][c0]+red[1][c0]+red[2][c0]+red[3][c0];
  if (blk==0 && t < NH){
    float a = 0.f;
    for (int d=0; d<64; ++d) a += bk[t*HD+d]*Wa[64+d];
    bkdot[t] = a;
  }
}

// K1: blocks [0,4096) lk rows; [4096,8160) ei rows
__global__ __launch_bounds__(256)
void lk_ei(const float* __restrict__ nv, const float* __restrict__ desc,
           const float* __restrict__ uk, const float* __restrict__ bkdot,
           const float* __restrict__ Wa,
           float* __restrict__ lk, float* __restrict__ ei){
  __shared__ float sh[ND];
  int blk = blockIdx.x;
  int wave = threadIdx.x >> 6, lane = threadIdx.x & 63;
  if (blk < NB*NS){
    int b = blk >> 7, j = blk & 127;
    const float* row = nv + (size_t)blk * ND;
    for (int c = threadIdx.x; c < ND; c += 256) sh[c] = row[c];
    __syncthreads();
    #pragma unroll
    for (int hh=0; hh<3; ++hh){
      int h = wave*3 + hh;
      float acc = 0.f;
      #pragma unroll
      for (int k=0; k<12; ++k) acc += sh[lane+64*k]*uk[h*ND + lane+64*k];
      acc = wredSum(acc);
      if (lane==0) lk[(b*NH + h)*NS + j] = acc + bkdot[h];
    }
  } else {
    int bs = blk - NB*NS;                 // 0..4063
    int b = bs / SD, s = bs % SD;
    float wea = Wa[128 + lane];
    const float* row = desc + (size_t)bs * ND;
    #pragma unroll
    for (int hh=0; hh<3; ++hh){
      int h = wave + hh*4;
      float v = row[h*HD + lane] * wea;
      v = wredSum(v);
      if (lane==0) ei[(b*NH + h)*NS + s] = v;
    }
  }
}

// K2: block = (b, jg of 16 j's), 256 blocks.  Recomputes all 24 softmax dists
// from lk/ei in LDS (redundant, ~3k exp), then m partials with float4 nv loads:
// each of 192 threads owns 4 c's, 16 loads x 96 FMA.  m_part[b][r][jg][c].
__global__ __launch_bounds__(256)
void msoft(const float* __restrict__ nv, const float* __restrict__ lk,
           const float* __restrict__ ei, float* __restrict__ m_part){
  int blk = blockIdx.x;               // b*8 + jg
  int b = blk >> 3, jg = blk & 7;
  int t = threadIdx.x, wave = t >> 6, lane = t & 63;
  __shared__ float slk[NH][NS];
  __shared__ float sei[NH][NS];
  __shared__ float wf[24][NS];
  for (int i=t; i<NH*NS; i+=256) ((float*)slk)[i] = lk[(size_t)b*NH*NS + i];
  for (int i=t; i<NH*NS; i+=256){
    int h = i >> 7, s = i & 127;
    sei[h][s] = (s < SD) ? ei[((size_t)b*NH + h)*NS + s] : 0.f;
  }
  __syncthreads();
  #pragma unroll
  for (int rr=0; rr<6; ++rr){
    int r = wave*6 + rr;
    int h = r >> 1, which = r & 1;
    const float* eirow = (which==0) ? sei[h%6] : sei[h];
    float g = (which==0) ? 1.f : (h>=6 ? 1.f : 0.f);
    float x0 = (lane>=1) ? slk[h][lane] + g*eirow[lane-1] : -3.0e38f;
    float x1 = slk[h][lane+64] + g*eirow[lane+63];
    float mm = wredMax(fmaxf(x0,x1));
    float e0 = (lane>=1) ? __expf(x0-mm) : 0.f;   // col 0 masked -> exactly 0
    float e1 = __expf(x1-mm);
    float s  = wredSum(e0+e1);
    float inv = 1.f/s;
    wf[r][lane]    = e0*inv;
    wf[r][lane+64] = e1*inv;
  }
  __syncthreads();
  if (t < 192){
    const float4* nvb = (const float4*)(nv + ((size_t)b*NS + jg*16)*ND);
    float4 acc[24];
    #pragma unroll
    for (int r=0; r<24; ++r) acc[r] = make_float4(0.f,0.f,0.f,0.f);
    #pragma unroll 2
    for (int jj=0; jj<16; ++jj){
      float4 x = nvb[jj*192 + t];
      int j = jg*16 + jj;
      #pragma unroll
      for (int r=0; r<24; ++r){
        float wr = wf[r][j];                      // broadcast, conflict-free
        acc[r].x += wr*x.x; acc[r].y += wr*x.y;
        acc[r].z += wr*x.z; acc[r].w += wr*x.w;
      }
    }
    #pragma unroll
    for (int r=0; r<24; ++r)
      ((float4*)(m_part + ((size_t)(b*24 + r)*8 + jg)*ND))[t] = acc[r];
  }
}

// K3: per (b,h), 512 threads: sum 8 m-partials -> V-projection -> recompute the
// 2 softmax rows -> write attn tile + basis slice (all 37.7 MB of output).
__global__ __launch_bounds__(512)
void proj_write(const float* __restrict__ m_part, const float* __restrict__ Wv,
                const float* __restrict__ bv, const float* __restrict__ lk,
                const float* __restrict__ ei, float* __restrict__ out){
  int bh = blockIdx.x;                // 0..383
  int b = bh / NH, h = bh % NH;
  int t = threadIdx.x, wave = t >> 6, lane = t & 63;
  __shared__ float msum[2][ND];
  __shared__ float w0[NS], w1[NS];
  __shared__ float cvec[2][HD];

  if (wave < 2){                      // recompute this (b,h)'s two dists
    const float* lkrow = lk + (size_t)bh*NS;
    const float* eirow = ei + ((size_t)b*NH + (wave==0 ? (h%6) : h))*NS;
    float g = (wave==0) ? 1.f : (h>=6 ? 1.f : 0.f);
    float x0 = (lane>=1) ? lkrow[lane] + g*eirow[lane-1] : -3.0e38f;
    float x1 = lkrow[lane+64] + g*eirow[lane+63];
    float mm = wredMax(fmaxf(x0,x1));
    float e0 = (lane>=1) ? __expf(x0-mm) : 0.f;
    float e1 = __expf(x1-mm);
    float s  = wredSum(e0+e1);
    float inv = 1.f/s;
    float* wd = wave ? w1 : w0;
    wd[lane]    = e0*inv;
    wd[lane+64] = e1*inv;
  }
  for (int i=t; i<2*ND; i+=512){
    int rl = (i >= ND);
    int c  = i - rl*ND;
    const float* mp = m_part + ((size_t)(b*24 + h*2 + rl)*8)*ND + c;
    float s = 0.f;
    #pragma unroll
    for (int g8=0; g8<8; ++g8) s += mp[(size_t)g8*ND];
    msum[rl][c] = s;
  }
  __syncthreads();
  #pragma unroll
  for (int dd=0; dd<8; ++dd){
    int d = wave*8 + dd;
    const float* wvr = Wv + (size_t)(h*HD + d)*ND;
    float p0=0.f, p1=0.f;
    #pragma unroll
    for (int k=0; k<12; ++k){
      float wv = wvr[lane + 64*k];
      p0 += wv*msum[0][lane + 64*k];
      p1 += wv*msum[1][lane + 64*k];
    }
    p0 = wredSum(p0); p1 = wredSum(p1);
    if (lane==0){
      float bb = bv[h*HD + d];
      cvec[0][d] = p0 + bb;
      cvec[1][d] = p1 + bb;
    }
  }
  __syncthreads();
  // attn tile: 128x128 floats = 4096 float4
  float4* ao = (float4*)(out + (size_t)NB*NS*ND + (size_t)bh*NS*NS);
  for (int idx=t; idx<4096; idx+=512){
    int i = idx>>5, q = idx&31;
    const float* src = (i==0) ? w0 : w1;
    float4 v = { src[q*4], src[q*4+1], src[q*4+2], src[q*4+3] };
    ao[idx] = v;
  }
  // basis slice: out[b][i][h*64 + q*4], 128 x 16 float4
  float* bo = out + (size_t)b*NS*ND + h*HD;
  for (int idx=t; idx<2048; idx+=512){
    int i = idx>>4, q = idx&15;
    const float* src = (i==0) ? cvec[0] : cvec[1];
    float4 v = { src[q*4], src[q*4+1], src[q*4+2], src[q*4+3] };
    *(float4*)(bo + (size_t)i*ND + q*4) = v;
  }
}

extern "C" void kernel_launch(void* const* d_in, const int* in_sizes, int n_in,
                              void* d_out, int out_size, void* d_ws, size_t ws_size,
                              hipStream_t stream) {
  const float* desc = (const float*)d_in[0];
  const float* nv   = (const float*)d_in[1];
  // d_in[2]=Wq, d_in[3]=bq: unused (softmax shift-invariance)
  const float* Wk   = (const float*)d_in[4];
  const float* bk   = (const float*)d_in[5];
  const float* Wv   = (const float*)d_in[6];
  const float* bv   = (const float*)d_in[7];
  const float* Wa   = (const float*)d_in[8];
  // d_in[9]=ba: unused (constant shift)
  float* out = (float*)d_out;
  float* ws  = (float*)d_ws;

  float* uk     = ws;               // 9216
  float* bkdot  = ws + 9216;        // 16
  float* ei     = ws + 9232;        // 49152
  float* lkbuf  = ws + 58384;       // 49152
  float* m_part = ws + 107536;      // 32*24*8*768 = 4718592  [b][r][jg][c]

  fold_k    <<<144,  256, 0, stream>>>(Wk, bk, Wa, uk, bkdot);
  lk_ei     <<<8160, 256, 0, stream>>>(nv, desc, uk, bkdot, Wa, lkbuf, ei);
  msoft     <<<256,  256, 0, stream>>>(nv, lkbuf, ei, m_part);
  proj_write<<<384,  512, 0, stream>>>(m_part, Wv, bv, lkbuf, ei, out);
}